// Round 1
// 495.910 us; speedup vs baseline: 1.1829x; 1.1829x over previous
//
#include <hip/hip_runtime.h>
#include <stdint.h>

// NVFP4 Linear fwd: y = dq(rht(x)) @ dq(rht(w))^T + bias
// Round plan:
//  (a) quant: LDS-staged coalescing (was: 64B-stride per-lane loads, ~1.3 TB/s)
//  (b) GEMM: 256x256 8-phase counted-vmcnt template (T2+T3+T4+T5), replacing
//      the m97 128^2 2-barrier structure (MfmaUtil 34% ceiling).

typedef __bf16 bf16x8 __attribute__((ext_vector_type(8)));
typedef float f32x4 __attribute__((ext_vector_type(4)));

// ---------------- quantization kernel ----------------

// RNE round of x (>=0) onto the e4m3fn grid (handles subnormals; no saturation
// needed: amax/6 << 448 for this problem).
__device__ __forceinline__ float e4m3_rt(float x) {
    unsigned int u = __float_as_uint(x);
    int ex = (int)((u >> 23) & 0xffu) - 127;
    if (ex < -6) ex = -6;                       // subnormal region: step 2^-9
    float qs = __uint_as_float((unsigned)(127 + 3 - ex) << 23);  // 2^(3-ex)
    float qi = __uint_as_float((unsigned)(127 + ex - 3) << 23);  // 2^(ex-3)
    return rintf(x * qs) * qi;                  // exact pow2 scaling, RNE ties-even
}

// Block-cooperative: 256 threads process 256 contiguous groups (16 KiB in,
// 8 KiB out). Global traffic fully coalesced; per-thread group access goes
// through LDS with involution chunk-swizzle pos = c ^ ((c>>3)&7)
// (conflict-free for both the linear write and the 4-chunk-per-thread read).
// Requires ngroups % 256 == 0 (true: M*K/16 and N*K/16 are powers of two).
__global__ __launch_bounds__(256) void quant_rht_kernel(
    const float* __restrict__ X, const float* __restrict__ signs,
    uint16_t* __restrict__ Q, int ngroups)
{
    (void)ngroups;
    __shared__ uint4 sbuf[1024];                 // 16 KiB
    const int t = threadIdx.x;
    const size_t gbase = (size_t)blockIdx.x * 256;

    // coalesced global -> LDS (swizzled position)
    const uint4* src = (const uint4*)(X + gbase * 16);
#pragma unroll
    for (int it = 0; it < 4; ++it) {
        int c = it * 256 + t;
        sbuf[c ^ ((c >> 3) & 7)] = src[c];
    }
    __syncthreads();

    // per-thread group = chunks 4t..4t+3
    float tv[16];
#pragma unroll
    for (int i = 0; i < 4; ++i) {
        int c = 4 * t + i;
        uint4 u = sbuf[c ^ ((c >> 3) & 7)];
        tv[4 * i + 0] = __uint_as_float(u.x);
        tv[4 * i + 1] = __uint_as_float(u.y);
        tv[4 * i + 2] = __uint_as_float(u.z);
        tv[4 * i + 3] = __uint_as_float(u.w);
    }

#pragma unroll
    for (int i = 0; i < 16; i++) tv[i] *= signs[i];

    // FWHT-16 (Sylvester order == block-doubled H), then *0.25 (orthonormal).
#pragma unroll
    for (int len = 1; len < 16; len <<= 1) {
#pragma unroll
        for (int i = 0; i < 16; i += 2 * len) {
#pragma unroll
            for (int j = 0; j < len; j++) {
                float a = tv[i + j], b = tv[i + j + len];
                tv[i + j] = a + b;
                tv[i + j + len] = a - b;
            }
        }
    }
    float amax = 0.0f;
#pragma unroll
    for (int i = 0; i < 16; i++) { tv[i] *= 0.25f; amax = fmaxf(amax, fabsf(tv[i])); }

    float scale = e4m3_rt(amax / 6.0f);
    float safe = (scale == 0.0f) ? 1.0f : scale;

    unsigned int w[8];
#pragma unroll
    for (int i = 0; i < 8; i++) {
        float d01[2];
#pragma unroll
        for (int h = 0; h < 2; h++) {
            float x = tv[2 * i + h];
            float aa = fminf(fabsf(x) / safe, 6.0f);
            // searchsorted(mids, aa, 'left'): ties round DOWN -> strict >
            float q = aa > 2.5f ? (aa > 5.0f ? 6.0f : (aa > 3.5f ? 4.0f : 3.0f))
                                : (aa > 1.25f ? (aa > 1.75f ? 2.0f : 1.5f)
                                              : (aa > 0.75f ? 1.0f
                                                 : (aa > 0.25f ? 0.5f : 0.0f)));
            d01[h] = copysignf(q * scale, x);   // exact in bf16
        }
        // exact bf16: low 16 bits of f32 are zero -> truncate
        w[i] = (__float_as_uint(d01[0]) >> 16) |
               (__float_as_uint(d01[1]) & 0xFFFF0000u);
    }

    __syncthreads();                 // all sbuf reads done before overwrite
    {
        int c0 = 2 * t, c1 = 2 * t + 1;
        sbuf[c0 ^ ((c0 >> 3) & 7)] = make_uint4(w[0], w[1], w[2], w[3]);
        sbuf[c1 ^ ((c1 >> 3) & 7)] = make_uint4(w[4], w[5], w[6], w[7]);
    }
    __syncthreads();

    // coalesced LDS -> global (512 x 16B = 8 KiB)
    uint4* dst = (uint4*)(Q + gbase * 16);
#pragma unroll
    for (int it = 0; it < 2; ++it) {
        int c = it * 256 + t;
        dst[c] = sbuf[c ^ ((c >> 3) & 7)];
    }
}

// ---------------- GEMM: C[M,N] = A[M,K] * B[N,K]^T + bias[N] ----------------
//
// 256x256 tile, BK=64, 512 threads = 8 waves (2M x 4N), per-wave 128x64 out.
// LDS = 8 half-tile slots x 16 KiB = 128 KiB. Half-tile = 256 rows x 32 K-cols
// (A/B split by K-half). Slot(h_j) = j & 7 where j = 4*tile + s,
// s: 0=A-kh0, 1=B-kh0, 2=A-kh1, 3=B-kh1 (tile parity = double buffer).
//
// Chunk swizzle (involution): 16B chunk c = row*4 + kc stored at c ^ ((c>>3)&7).
// gload_lds dest stays LINEAR (p = L*512 + tid); global SOURCE is
// inverse-swizzled; ds_read uses the swizzled position (T2, both-sides rule).
//
// Schedule: 8 phases / 2 K-tiles. Phase q: {ds_read frags; stage h_{8i+5+q};
// s_barrier; lgkmcnt(0); setprio(1); 16 MFMA; setprio(0); [vmcnt(4) @ q=4,8];
// s_barrier}. Prologue stages h0..h5 + vmcnt(4). Every slot overwrite lands
// >=1 barrier after the previous reader's lgkmcnt(0) drain (checked per q).
// Tail: stages past NHT clamp to koff=0 (in-bounds dummy; keeps vmcnt exact).

#define BM 256
#define BN 256

__global__ __launch_bounds__(512, 2) void gemm_bt_bias(
    const uint16_t* __restrict__ A,   // bf16 bits, [M,K]
    const uint16_t* __restrict__ B,   // bf16 bits, [N,K]
    const float* __restrict__ bias,   // [N]
    float* __restrict__ C,            // [M,N]
    int M, int N, int K)
{
    __shared__ uint4 sh[8][1024];     // 128 KiB

    const int tid  = threadIdx.x;
    const int lane = tid & 63;
    const int wave = tid >> 6;
    const int wm = wave >> 2, wn = wave & 3;
    const int lm = lane & 15, g4 = lane >> 4;
    const int bn = blockIdx.x, bm = blockIdx.y;

    const int NT  = K >> 6;           // K-tiles (BK=64); K % 128 == 0 assumed
    const int NHT = NT << 2;          // half-tiles total

    // ---- staging precompute: LDS pos p -> source chunk c = p ^ ((p>>3)&7)
    const int p0 = tid, p1 = 512 + tid;
    const int c0 = p0 ^ ((p0 >> 3) & 7);
    const int c1 = p1 ^ ((p1 >> 3) & 7);
    const uint16_t* asrc0 = A + (size_t)(bm * BM + (c0 >> 2)) * K + (c0 & 3) * 8;
    const uint16_t* asrc1 = A + (size_t)(bm * BM + (c1 >> 2)) * K + (c1 & 3) * 8;
    const uint16_t* bsrc0 = B + (size_t)(bn * BN + (c0 >> 2)) * K + (c0 & 3) * 8;
    const uint16_t* bsrc1 = B + (size_t)(bn * BN + (c1 >> 2)) * K + (c1 & 3) * 8;
    char* ldsd0 = (char*)&sh[0][0] + p0 * 16;
    char* ldsd1 = (char*)&sh[0][0] + p1 * 16;

    // ---- swizzled ds_read chunk positions (per-thread constants)
    int aPos[8], bPos[4];
#pragma unroll
    for (int f = 0; f < 8; ++f) {
        int c = (wm * 128 + f * 16 + lm) * 4 + g4;
        aPos[f] = c ^ ((c >> 3) & 7);
    }
#pragma unroll
    for (int f = 0; f < 4; ++f) {
        int c = (wn * 64 + f * 16 + lm) * 4 + g4;
        bPos[f] = c ^ ((c >> 3) & 7);
    }

    f32x4 acc[8][4];
#pragma unroll
    for (int i = 0; i < 8; ++i)
#pragma unroll
        for (int j = 0; j < 4; ++j) acc[i][j] = (f32x4){0.f, 0.f, 0.f, 0.f};
    bf16x8 bfr[4];   // B frags persist across the rh=0 -> rh=1 phase pair

#define STAGE(jj) do {                                                        \
    int _j = (jj);                                                            \
    int _koff = (_j < NHT) ? (((_j >> 2) << 6) | (((_j >> 1) & 1) << 5)) : 0; \
    int _sb = (_j & 7) << 14;                                                 \
    const uint16_t* _s0 = (_j & 1) ? bsrc0 : asrc0;                           \
    const uint16_t* _s1 = (_j & 1) ? bsrc1 : asrc1;                           \
    __builtin_amdgcn_global_load_lds(                                         \
        (const __attribute__((address_space(1))) unsigned int*)(_s0 + _koff), \
        (__attribute__((address_space(3))) unsigned int*)(ldsd0 + _sb),       \
        16, 0, 0);                                                            \
    __builtin_amdgcn_global_load_lds(                                         \
        (const __attribute__((address_space(1))) unsigned int*)(_s1 + _koff), \
        (__attribute__((address_space(3))) unsigned int*)(ldsd1 + _sb),       \
        16, 0, 0);                                                            \
} while (0)

#define PHASE(PAR, KS, RH, Q, GATE) do {                                      \
    bf16x8 af_[4];                                                            \
    _Pragma("unroll")                                                         \
    for (int _i = 0; _i < 4; ++_i)                                            \
        af_[_i] = __builtin_bit_cast(bf16x8,                                  \
            sh[4*(PAR) + 2*(KS)][aPos[4*(RH) + _i]]);                         \
    if ((Q) & 1) {                                                            \
        _Pragma("unroll")                                                     \
        for (int _jj = 0; _jj < 4; ++_jj)                                     \
            bfr[_jj] = __builtin_bit_cast(bf16x8,                             \
                sh[4*(PAR) + 2*(KS) + 1][bPos[_jj]]);                         \
    }                                                                         \
    STAGE(hb + 5 + (Q));                                                      \
    __builtin_amdgcn_s_barrier();                                             \
    asm volatile("s_waitcnt lgkmcnt(0)" ::: "memory");                        \
    __builtin_amdgcn_s_setprio(1);                                            \
    _Pragma("unroll")                                                         \
    for (int _i = 0; _i < 4; ++_i)                                            \
        _Pragma("unroll")                                                     \
        for (int _jj = 0; _jj < 4; ++_jj)                                     \
            acc[4*(RH) + _i][_jj] = __builtin_amdgcn_mfma_f32_16x16x32_bf16(  \
                af_[_i], bfr[_jj], acc[4*(RH) + _i][_jj], 0, 0, 0);           \
    __builtin_amdgcn_s_setprio(0);                                            \
    if (GATE) asm volatile("s_waitcnt vmcnt(4)" ::: "memory");                \
    __builtin_amdgcn_s_barrier();                                             \
} while (0)

    // prologue: stage h0..h5; ensure tile 0 (h0..h3) landed
    STAGE(0); STAGE(1); STAGE(2); STAGE(3); STAGE(4); STAGE(5);
    asm volatile("s_waitcnt vmcnt(4)" ::: "memory");
    __builtin_amdgcn_s_barrier();

    const int NT2 = NT >> 1;
    for (int it2 = 0; it2 < NT2; ++it2) {
        const int hb = it2 << 3;
        PHASE(0, 0, 0, 1, 0);
        PHASE(0, 0, 1, 2, 0);
        PHASE(0, 1, 0, 3, 0);
        PHASE(0, 1, 1, 4, 1);
        PHASE(1, 0, 0, 5, 0);
        PHASE(1, 0, 1, 6, 0);
        PHASE(1, 1, 0, 7, 0);
        PHASE(1, 1, 1, 8, 1);
    }
    // drain dummy tail stages before LDS goes away
    asm volatile("s_waitcnt vmcnt(0)" ::: "memory");

#undef PHASE
#undef STAGE

    // Epilogue. C/D layout: col = lane&15, row = (lane>>4)*4 + reg  [m89/m91]
#pragma unroll
    for (int j = 0; j < 4; ++j) {
        int col = bn * BN + wn * 64 + j * 16 + lm;
        float bj = bias[col];
#pragma unroll
        for (int i = 0; i < 8; ++i) {
            int row0 = bm * BM + wm * 128 + i * 16 + g4 * 4;
#pragma unroll
            for (int r = 0; r < 4; ++r) {
                C[(size_t)(row0 + r) * (size_t)N + col] = acc[i][j][r] + bj;
            }
        }
    }
}

// ---------------- launch ----------------

extern "C" void kernel_launch(void* const* d_in, const int* in_sizes, int n_in,
                              void* d_out, int out_size, void* d_ws, size_t ws_size,
                              hipStream_t stream)
{
    const float* x        = (const float*)d_in[0];
    const float* w        = (const float*)d_in[1];
    const float* bias     = (const float*)d_in[2];
    const float* signs_in = (const float*)d_in[3];
    // d_in[4] = signs_grad: unused in forward

    const int OUT = in_sizes[2];              // 4096
    const int IN  = in_sizes[1] / OUT;        // 4096
    const int M   = in_sizes[0] / IN;         // 8192

    uint16_t* xq = (uint16_t*)d_ws;                    // [M, IN] bf16
    uint16_t* wq = xq + (size_t)M * (size_t)IN;        // [OUT, IN] bf16
    (void)ws_size; (void)n_in; (void)out_size;

    int ngx = (int)((size_t)M * IN / 16);
    int ngw = (int)((size_t)OUT * IN / 16);
    quant_rht_kernel<<<ngx / 256, 256, 0, stream>>>(x, signs_in, xq, ngx);
    quant_rht_kernel<<<ngw / 256, 256, 0, stream>>>(w, signs_in, wq, ngw);

    dim3 grid(OUT / BN, M / BM);
    gemm_bt_bias<<<grid, 512, 0, stream>>>(xq, wq, bias, (float*)d_out, M, OUT, IN);
}

// Round 2
// 487.671 us; speedup vs baseline: 1.2029x; 1.0169x over previous
//
#include <hip/hip_runtime.h>
#include <stdint.h>

// NVFP4 Linear fwd: y = dq(rht(x)) @ dq(rht(w))^T + bias
// Round plan:
//  (a) quant: revert to direct per-thread version (LDS staging was -20us) and
//      hand-unroll FWHT into named scalars (rule #20: kill any scratch risk).
//  (b) GEMM: register-pipelined fragment reads (one window lookahead, static
//      A/B bank double-buffer) + ONE barrier per window + vmcnt(4) gates at
//      odd windows. MFMA no longer waits on same-window LDS reads.

typedef __bf16 bf16x8 __attribute__((ext_vector_type(8)));
typedef float f32x4 __attribute__((ext_vector_type(4)));

// ---------------- quantization kernel ----------------

// RNE round of x (>=0) onto the e4m3fn grid (handles subnormals; no saturation
// needed: amax/6 << 448 for this problem).
__device__ __forceinline__ float e4m3_rt(float x) {
    unsigned int u = __float_as_uint(x);
    int ex = (int)((u >> 23) & 0xffu) - 127;
    if (ex < -6) ex = -6;                       // subnormal region: step 2^-9
    float qs = __uint_as_float((unsigned)(127 + 3 - ex) << 23);  // 2^(3-ex)
    float qi = __uint_as_float((unsigned)(127 + ex - 3) << 23);  // 2^(ex-3)
    return rintf(x * qs) * qi;                  // exact pow2 scaling, RNE ties-even
}

__device__ __forceinline__ float quant1(float tv, float safe, float scale) {
    float aa = fminf(fabsf(tv) / safe, 6.0f);
    // searchsorted(mids, aa, 'left'): ties round DOWN -> strict >
    float q = aa > 2.5f ? (aa > 5.0f ? 6.0f : (aa > 3.5f ? 4.0f : 3.0f))
                        : (aa > 1.25f ? (aa > 1.75f ? 2.0f : 1.5f)
                                      : (aa > 0.75f ? 1.0f
                                         : (aa > 0.25f ? 0.5f : 0.0f)));
    return copysignf(q * scale, tv);            // exact in bf16
}

__device__ __forceinline__ unsigned pack2(float lo, float hi) {
    // exact bf16: low 16 bits of f32 are zero -> truncate
    return (__float_as_uint(lo) >> 16) | (__float_as_uint(hi) & 0xFFFF0000u);
}

__global__ __launch_bounds__(256) void quant_rht_kernel(
    const float* __restrict__ X, const float* __restrict__ signs,
    uint16_t* __restrict__ Q, int ngroups)
{
    int gid = blockIdx.x * 256 + threadIdx.x;
    if (gid >= ngroups) return;

    const float4* p = (const float4*)(X + (size_t)gid * 16);
    float4 v0 = p[0], v1 = p[1], v2 = p[2], v3 = p[3];
    const float4* sp = (const float4*)signs;
    float4 s0 = sp[0], s1 = sp[1], s2 = sp[2], s3 = sp[3];

    float t0 = v0.x * s0.x, t1 = v0.y * s0.y, t2 = v0.z * s0.z, t3 = v0.w * s0.w;
    float t4 = v1.x * s1.x, t5 = v1.y * s1.y, t6 = v1.z * s1.z, t7 = v1.w * s1.w;
    float t8 = v2.x * s2.x, t9 = v2.y * s2.y, t10 = v2.z * s2.z, t11 = v2.w * s2.w;
    float t12 = v3.x * s3.x, t13 = v3.y * s3.y, t14 = v3.z * s3.z, t15 = v3.w * s3.w;

    // FWHT-16, fully hand-unrolled into named scalars (no arrays -> no scratch).
#define BT(a, b) { float _s = (a) + (b), _d = (a) - (b); (a) = _s; (b) = _d; }
    BT(t0,t1)  BT(t2,t3)  BT(t4,t5)   BT(t6,t7)
    BT(t8,t9)  BT(t10,t11) BT(t12,t13) BT(t14,t15)
    BT(t0,t2)  BT(t1,t3)  BT(t4,t6)   BT(t5,t7)
    BT(t8,t10) BT(t9,t11) BT(t12,t14) BT(t13,t15)
    BT(t0,t4)  BT(t1,t5)  BT(t2,t6)   BT(t3,t7)
    BT(t8,t12) BT(t9,t13) BT(t10,t14) BT(t11,t15)
    BT(t0,t8)  BT(t1,t9)  BT(t2,t10)  BT(t3,t11)
    BT(t4,t12) BT(t5,t13) BT(t6,t14)  BT(t7,t15)
#undef BT

    t0 *= 0.25f;  t1 *= 0.25f;  t2 *= 0.25f;  t3 *= 0.25f;
    t4 *= 0.25f;  t5 *= 0.25f;  t6 *= 0.25f;  t7 *= 0.25f;
    t8 *= 0.25f;  t9 *= 0.25f;  t10 *= 0.25f; t11 *= 0.25f;
    t12 *= 0.25f; t13 *= 0.25f; t14 *= 0.25f; t15 *= 0.25f;

    float amax = fmaxf(
        fmaxf(fmaxf(fmaxf(fabsf(t0), fabsf(t1)), fmaxf(fabsf(t2), fabsf(t3))),
              fmaxf(fmaxf(fabsf(t4), fabsf(t5)), fmaxf(fabsf(t6), fabsf(t7)))),
        fmaxf(fmaxf(fmaxf(fabsf(t8), fabsf(t9)), fmaxf(fabsf(t10), fabsf(t11))),
              fmaxf(fmaxf(fabsf(t12), fabsf(t13)), fmaxf(fabsf(t14), fabsf(t15)))));

    float scale = e4m3_rt(amax / 6.0f);
    float safe = (scale == 0.0f) ? 1.0f : scale;

    unsigned w0 = pack2(quant1(t0, safe, scale),  quant1(t1, safe, scale));
    unsigned w1 = pack2(quant1(t2, safe, scale),  quant1(t3, safe, scale));
    unsigned w2 = pack2(quant1(t4, safe, scale),  quant1(t5, safe, scale));
    unsigned w3 = pack2(quant1(t6, safe, scale),  quant1(t7, safe, scale));
    unsigned w4 = pack2(quant1(t8, safe, scale),  quant1(t9, safe, scale));
    unsigned w5 = pack2(quant1(t10, safe, scale), quant1(t11, safe, scale));
    unsigned w6 = pack2(quant1(t12, safe, scale), quant1(t13, safe, scale));
    unsigned w7 = pack2(quant1(t14, safe, scale), quant1(t15, safe, scale));

    uint4* q4 = (uint4*)(Q + (size_t)gid * 16);
    q4[0] = make_uint4(w0, w1, w2, w3);
    q4[1] = make_uint4(w4, w5, w6, w7);
}

// ---------------- GEMM: C[M,N] = A[M,K] * B[N,K]^T + bias[N] ----------------
//
// 256x256 tile, BK=64, 512 threads = 8 waves (2M x 4N), per-wave 128x64 out.
// LDS = 8 half-tile slots x 16 KiB. Half-tile = 256 rows x 32 K-cols.
// Slot(h_j) = j & 7; j = 4*tile + {0:A-kh0, 1:B-kh0, 2:A-kh1, 3:B-kh1}.
//
// Chunk swizzle (involution): chunk c = row*4 + kc stored at c ^ ((c>>3)&7).
// gload_lds dest LINEAR; global source inverse-swizzled; ds_read swizzled.
//
// Register-pipelined schedule, ONE barrier per window:
//   window q: [issue ds_reads for window q+1 into bank (q+1)&1]
//             [STAGE h_{hb+5+q}] [odd q: vmcnt(4)] [sched_barrier]
//             [setprio(1); 16 MFMA on bank q&1; setprio(0)] [s_barrier]
// MFMA(q)'s operands were issued at q-1 and are lgkm-complete -> no LDS/MFMA
// serialization. Gate derivation (vmcnt(4) = 2 half-tiles in flight, after
// odd window's STAGE): gate q1 -> h+4 landed (q2 reads h+2,h+3); q3 -> h+6
// (q4 reads h+4,h+5); q5 -> h+8 (q6 reads h+6,h+7); q7 -> h+10 (q8 reads
// h+8,h+9). Cross-wave publication via the window-ending barrier. WAR slot
// reuse margin >= 2 windows (checked per slot). Tail stages clamp to koff=0.

#define BM 256
#define BN 256

__global__ __launch_bounds__(512, 2) void gemm_bt_bias(
    const uint16_t* __restrict__ A,   // bf16 bits, [M,K]
    const uint16_t* __restrict__ B,   // bf16 bits, [N,K]
    const float* __restrict__ bias,   // [N]
    float* __restrict__ C,            // [M,N]
    int M, int N, int K)
{
    __shared__ uint4 sh[8][1024];     // 128 KiB

    const int tid  = threadIdx.x;
    const int lane = tid & 63;
    const int wave = tid >> 6;
    const int wm = wave >> 2, wn = wave & 3;
    const int lm = lane & 15, g4 = lane >> 4;
    const int bn = blockIdx.x, bm = blockIdx.y;

    const int NT  = K >> 6;           // K-tiles (BK=64); K % 128 == 0 assumed
    const int NHT = NT << 2;          // half-tiles total

    // ---- staging precompute: LDS pos p -> source chunk c = p ^ ((p>>3)&7)
    const int p0 = tid, p1 = 512 + tid;
    const int c0 = p0 ^ ((p0 >> 3) & 7);
    const int c1 = p1 ^ ((p1 >> 3) & 7);
    const uint16_t* asrc0 = A + (size_t)(bm * BM + (c0 >> 2)) * K + (c0 & 3) * 8;
    const uint16_t* asrc1 = A + (size_t)(bm * BM + (c1 >> 2)) * K + (c1 & 3) * 8;
    const uint16_t* bsrc0 = B + (size_t)(bn * BN + (c0 >> 2)) * K + (c0 & 3) * 8;
    const uint16_t* bsrc1 = B + (size_t)(bn * BN + (c1 >> 2)) * K + (c1 & 3) * 8;
    char* ldsd0 = (char*)&sh[0][0] + p0 * 16;
    char* ldsd1 = (char*)&sh[0][0] + p1 * 16;

    // ---- swizzled ds_read chunk positions (per-thread constants)
    int aPos[8], bPos[4];
#pragma unroll
    for (int f = 0; f < 8; ++f) {
        int c = (wm * 128 + f * 16 + lm) * 4 + g4;
        aPos[f] = c ^ ((c >> 3) & 7);
    }
#pragma unroll
    for (int f = 0; f < 4; ++f) {
        int c = (wn * 64 + f * 16 + lm) * 4 + g4;
        bPos[f] = c ^ ((c >> 3) & 7);
    }

    f32x4 acc[8][4];
#pragma unroll
    for (int i = 0; i < 8; ++i)
#pragma unroll
        for (int j = 0; j < 4; ++j) acc[i][j] = (f32x4){0.f, 0.f, 0.f, 0.f};

    bf16x8 a0[4], a1[4], b0[4], b1[4];   // static frag double-buffers

#define STAGE(jj) do {                                                        \
    int _j = (jj);                                                            \
    int _koff = (_j < NHT) ? (((_j >> 2) << 6) | (((_j >> 1) & 1) << 5)) : 0; \
    int _sb = (_j & 7) << 14;                                                 \
    const uint16_t* _s0 = (_j & 1) ? bsrc0 : asrc0;                           \
    const uint16_t* _s1 = (_j & 1) ? bsrc1 : asrc1;                           \
    __builtin_amdgcn_global_load_lds(                                         \
        (const __attribute__((address_space(1))) unsigned int*)(_s0 + _koff), \
        (__attribute__((address_space(3))) unsigned int*)(ldsd0 + _sb),       \
        16, 0, 0);                                                            \
    __builtin_amdgcn_global_load_lds(                                         \
        (const __attribute__((address_space(1))) unsigned int*)(_s1 + _koff), \
        (__attribute__((address_space(3))) unsigned int*)(ldsd1 + _sb),       \
        16, 0, 0);                                                            \
} while (0)

// WIN(ARH, CA, CB, NA, NSA, NRH, LOADB, NB, NSB, SJ, GATE)
//   compute: acc rows 4*ARH.. with frags CA x CB (loaded last window)
//   load:    NA <- A slot NSA rows 4*NRH.. ; if LOADB: NB <- B slot NSB
#define WIN(ARH, CA, CB, NA, NSA, NRH, LOADB, NB, NSB, SJ, GATE) do {         \
    _Pragma("unroll")                                                         \
    for (int _i = 0; _i < 4; ++_i)                                            \
        NA[_i] = __builtin_bit_cast(bf16x8, sh[NSA][aPos[4*(NRH) + _i]]);     \
    if (LOADB) {                                                              \
        _Pragma("unroll")                                                     \
        for (int _jj = 0; _jj < 4; ++_jj)                                     \
            NB[_jj] = __builtin_bit_cast(bf16x8, sh[NSB][bPos[_jj]]);         \
    }                                                                         \
    STAGE(hb + (SJ));                                                         \
    if (GATE) asm volatile("s_waitcnt vmcnt(4)" ::: "memory");                \
    __builtin_amdgcn_sched_barrier(0);                                        \
    __builtin_amdgcn_s_setprio(1);                                            \
    _Pragma("unroll")                                                         \
    for (int _i = 0; _i < 4; ++_i)                                            \
        _Pragma("unroll")                                                     \
        for (int _jj = 0; _jj < 4; ++_jj)                                     \
            acc[4*(ARH) + _i][_jj] = __builtin_amdgcn_mfma_f32_16x16x32_bf16( \
                CA[_i], CB[_jj], acc[4*(ARH) + _i][_jj], 0, 0, 0);            \
    __builtin_amdgcn_s_setprio(0);                                            \
    __builtin_amdgcn_sched_barrier(0);                                        \
    __builtin_amdgcn_s_barrier();                                             \
} while (0)

    // prologue: stage h0..h5; h0,h1 landed; publish; preload window-1 frags
    STAGE(0); STAGE(1); STAGE(2); STAGE(3); STAGE(4); STAGE(5);
    asm volatile("s_waitcnt vmcnt(8)" ::: "memory");
    __builtin_amdgcn_s_barrier();
#pragma unroll
    for (int i = 0; i < 4; ++i)
        a1[i] = __builtin_bit_cast(bf16x8, sh[0][aPos[i]]);
#pragma unroll
    for (int j = 0; j < 4; ++j)
        b0[j] = __builtin_bit_cast(bf16x8, sh[1][bPos[j]]);

    const int NT2 = NT >> 1;
    for (int it2 = 0; it2 < NT2; ++it2) {
        const int hb = it2 << 3;
        WIN(0, a1, b0, a0, 0, 1, 0, b1, 0,  6, 1);   // q1 (0,0,rh0)
        WIN(1, a0, b0, a1, 2, 0, 1, b1, 3,  7, 0);   // q2 (0,0,rh1)
        WIN(0, a1, b1, a0, 2, 1, 0, b0, 0,  8, 1);   // q3 (0,1,rh0)
        WIN(1, a0, b1, a1, 4, 0, 1, b0, 5,  9, 0);   // q4 (0,1,rh1)
        WIN(0, a1, b0, a0, 4, 1, 0, b1, 0, 10, 1);   // q5 (1,0,rh0)
        WIN(1, a0, b0, a1, 6, 0, 1, b1, 7, 11, 0);   // q6 (1,0,rh1)
        WIN(0, a1, b1, a0, 6, 1, 0, b0, 0, 12, 1);   // q7 (1,1,rh0)
        WIN(1, a0, b1, a1, 0, 0, 1, b0, 1, 13, 0);   // q8 (1,1,rh1)
    }
    asm volatile("s_waitcnt vmcnt(0) lgkmcnt(0)" ::: "memory");

#undef WIN
#undef STAGE

    // Epilogue. C/D layout: col = lane&15, row = (lane>>4)*4 + reg  [m89/m91]
#pragma unroll
    for (int j = 0; j < 4; ++j) {
        int col = bn * BN + wn * 64 + j * 16 + lm;
        float bj = bias[col];
#pragma unroll
        for (int i = 0; i < 8; ++i) {
            int row0 = bm * BM + wm * 128 + i * 16 + g4 * 4;
#pragma unroll
            for (int r = 0; r < 4; ++r) {
                C[(size_t)(row0 + r) * (size_t)N + col] = acc[i][j][r] + bj;
            }
        }
    }
}

// ---------------- launch ----------------

extern "C" void kernel_launch(void* const* d_in, const int* in_sizes, int n_in,
                              void* d_out, int out_size, void* d_ws, size_t ws_size,
                              hipStream_t stream)
{
    const float* x        = (const float*)d_in[0];
    const float* w        = (const float*)d_in[1];
    const float* bias     = (const float*)d_in[2];
    const float* signs_in = (const float*)d_in[3];
    // d_in[4] = signs_grad: unused in forward

    const int OUT = in_sizes[2];              // 4096
    const int IN  = in_sizes[1] / OUT;        // 4096
    const int M   = in_sizes[0] / IN;         // 8192

    uint16_t* xq = (uint16_t*)d_ws;                    // [M, IN] bf16
    uint16_t* wq = xq + (size_t)M * (size_t)IN;        // [OUT, IN] bf16
    (void)ws_size; (void)n_in; (void)out_size;

    int ngx = (int)((size_t)M * IN / 16);
    int ngw = (int)((size_t)OUT * IN / 16);
    quant_rht_kernel<<<(ngx + 255) / 256, 256, 0, stream>>>(x, signs_in, xq, ngx);
    quant_rht_kernel<<<(ngw + 255) / 256, 256, 0, stream>>>(w, signs_in, wq, ngw);

    dim3 grid(OUT / BN, M / BM);
    gemm_bt_bias<<<grid, 512, 0, stream>>>(xq, wq, bias, (float*)d_out, M, OUT, IN);
}

// Round 3
// 473.410 us; speedup vs baseline: 1.2392x; 1.0301x over previous
//
#include <hip/hip_runtime.h>
#include <stdint.h>

// NVFP4 Linear fwd: y = dq(rht(x)) @ dq(rht(w))^T + bias
// Round plan:
//  (a) quant: replace 16 IEEE f32 divisions/thread with exact threshold
//      compares |t| > c*safe (c*safe exact: 3-bit mids x 4-bit e4m3 scale;
//      proven bit-equivalent to round(|t|/safe) > c).
//  (b) GEMM: window reorder -- MFMA burst FIRST (operands from last window),
//      then ds_reads/STAGE/gate. No sched_barrier between MFMA and loads, so
//      the compiler interleaves loads under the MFMA shadow. Gates deepened
//      vmcnt(4) -> vmcnt(6) (3 half-tiles in flight, m201 depth).

typedef __bf16 bf16x8 __attribute__((ext_vector_type(8)));
typedef float f32x4 __attribute__((ext_vector_type(4)));

// ---------------- quantization kernel ----------------

// RNE round of x (>=0) onto the e4m3fn grid (handles subnormals; no saturation
// needed: amax/6 << 448 for this problem).
__device__ __forceinline__ float e4m3_rt(float x) {
    unsigned int u = __float_as_uint(x);
    int ex = (int)((u >> 23) & 0xffu) - 127;
    if (ex < -6) ex = -6;                       // subnormal region: step 2^-9
    float qs = __uint_as_float((unsigned)(127 + 3 - ex) << 23);  // 2^(3-ex)
    float qi = __uint_as_float((unsigned)(127 + ex - 3) << 23);  // 2^(ex-3)
    return rintf(x * qs) * qi;                  // exact pow2 scaling, RNE ties-even
}

__device__ __forceinline__ unsigned pack2(float lo, float hi) {
    // exact bf16: low 16 bits of f32 are zero -> truncate
    return (__float_as_uint(lo) >> 16) | (__float_as_uint(hi) & 0xFFFF0000u);
}

__global__ __launch_bounds__(256) void quant_rht_kernel(
    const float* __restrict__ X, const float* __restrict__ signs,
    uint16_t* __restrict__ Q, int ngroups)
{
    int gid = blockIdx.x * 256 + threadIdx.x;
    if (gid >= ngroups) return;

    const float4* p = (const float4*)(X + (size_t)gid * 16);
    float4 v0 = p[0], v1 = p[1], v2 = p[2], v3 = p[3];
    const float4* sp = (const float4*)signs;
    float4 s0 = sp[0], s1 = sp[1], s2 = sp[2], s3 = sp[3];

    float t0 = v0.x * s0.x, t1 = v0.y * s0.y, t2 = v0.z * s0.z, t3 = v0.w * s0.w;
    float t4 = v1.x * s1.x, t5 = v1.y * s1.y, t6 = v1.z * s1.z, t7 = v1.w * s1.w;
    float t8 = v2.x * s2.x, t9 = v2.y * s2.y, t10 = v2.z * s2.z, t11 = v2.w * s2.w;
    float t12 = v3.x * s3.x, t13 = v3.y * s3.y, t14 = v3.z * s3.z, t15 = v3.w * s3.w;

    // FWHT-16, hand-unrolled into named scalars.
#define BT(a, b) { float _s = (a) + (b), _d = (a) - (b); (a) = _s; (b) = _d; }
    BT(t0,t1)  BT(t2,t3)  BT(t4,t5)   BT(t6,t7)
    BT(t8,t9)  BT(t10,t11) BT(t12,t13) BT(t14,t15)
    BT(t0,t2)  BT(t1,t3)  BT(t4,t6)   BT(t5,t7)
    BT(t8,t10) BT(t9,t11) BT(t12,t14) BT(t13,t15)
    BT(t0,t4)  BT(t1,t5)  BT(t2,t6)   BT(t3,t7)
    BT(t8,t12) BT(t9,t13) BT(t10,t14) BT(t11,t15)
    BT(t0,t8)  BT(t1,t9)  BT(t2,t10)  BT(t3,t11)
    BT(t4,t12) BT(t5,t13) BT(t6,t14)  BT(t7,t15)
#undef BT

    t0 *= 0.25f;  t1 *= 0.25f;  t2 *= 0.25f;  t3 *= 0.25f;
    t4 *= 0.25f;  t5 *= 0.25f;  t6 *= 0.25f;  t7 *= 0.25f;
    t8 *= 0.25f;  t9 *= 0.25f;  t10 *= 0.25f; t11 *= 0.25f;
    t12 *= 0.25f; t13 *= 0.25f; t14 *= 0.25f; t15 *= 0.25f;

    float amax = fmaxf(
        fmaxf(fmaxf(fmaxf(fabsf(t0), fabsf(t1)), fmaxf(fabsf(t2), fabsf(t3))),
              fmaxf(fmaxf(fabsf(t4), fabsf(t5)), fmaxf(fabsf(t6), fabsf(t7)))),
        fmaxf(fmaxf(fmaxf(fabsf(t8), fabsf(t9)), fmaxf(fabsf(t10), fabsf(t11))),
              fmaxf(fmaxf(fabsf(t12), fabsf(t13)), fmaxf(fabsf(t14), fabsf(t15)))));

    float scale = e4m3_rt(amax / 6.0f);         // keep exact IEEE div (1/group)
    float safe = (scale == 0.0f) ? 1.0f : scale;

    // Exact decision thresholds: mids (<=3 significand bits) x e4m3 safe
    // (<=4 bits) -> products exact in f32. |t| > c*safe  <=>  reference's
    // searchsorted-left on round(|t|/safe) (ulp argument; ties round down).
    float m1 = 0.25f * safe, m2 = 0.75f * safe, m3 = 1.25f * safe,
          m4 = 1.75f * safe, m5 = 2.5f * safe,  m6 = 3.5f * safe,
          m7 = 5.0f * safe;

#define Q1(tv) ({                                                              \
    float _a = fabsf(tv);                                                      \
    float _q = _a > m5 ? (_a > m7 ? 6.0f : (_a > m6 ? 4.0f : 3.0f))            \
                       : (_a > m3 ? (_a > m4 ? 2.0f : 1.5f)                    \
                                  : (_a > m2 ? 1.0f : (_a > m1 ? 0.5f : 0.0f)));\
    copysignf(_q * scale, (tv)); })

    unsigned w0 = pack2(Q1(t0),  Q1(t1));
    unsigned w1 = pack2(Q1(t2),  Q1(t3));
    unsigned w2 = pack2(Q1(t4),  Q1(t5));
    unsigned w3 = pack2(Q1(t6),  Q1(t7));
    unsigned w4 = pack2(Q1(t8),  Q1(t9));
    unsigned w5 = pack2(Q1(t10), Q1(t11));
    unsigned w6 = pack2(Q1(t12), Q1(t13));
    unsigned w7 = pack2(Q1(t14), Q1(t15));
#undef Q1

    uint4* q4 = (uint4*)(Q + (size_t)gid * 16);
    q4[0] = make_uint4(w0, w1, w2, w3);
    q4[1] = make_uint4(w4, w5, w6, w7);
}

// ---------------- GEMM: C[M,N] = A[M,K] * B[N,K]^T + bias[N] ----------------
//
// 256x256 tile, BK=64, 512 threads = 8 waves (2M x 4N), per-wave 128x64 out.
// LDS = 8 half-tile slots x 16 KiB. Half-tile = 256 rows x 32 K-cols.
// Slot(h_j) = j & 7; j = 4*tile + {0:A-kh0, 1:B-kh0, 2:A-kh1, 3:B-kh1}.
//
// Chunk swizzle (involution): chunk c = row*4 + kc stored at c ^ ((c>>3)&7).
// gload_lds dest LINEAR; global source inverse-swizzled; ds_read swizzled.
//
// Window (one barrier each):
//   [setprio(1); 16 MFMA on frags read LAST window; setprio(0)]
//   [ds_reads for next window into alternate bank] [STAGE h_{hb+SJ}]
//   [odd windows: vmcnt(6)] [sched_barrier] [s_barrier]
// MFMA first: no dependence on this window's loads -> pipe fed immediately;
// compiler interleaves loads into the MFMA shadow (no sched_barrier between).
// Gate derivation (vmcnt(6) = 3 half-tiles in flight, after window's STAGE):
//   q1 (staged h+6) -> h+3 landed (q2 reads h+2,h+3);
//   q3 (staged h+8) -> h+5 landed (q4 reads h+4,h+5);
//   q5 (staged h+10) -> h+7     ; q7 (staged h+12) -> h+9 (q8 reads h+8,h+9).
// WAR slot-reuse margin >= 2 windows (unchanged). Tail stages clamp to koff=0.

#define BM 256
#define BN 256

__global__ __launch_bounds__(512, 2) void gemm_bt_bias(
    const uint16_t* __restrict__ A,   // bf16 bits, [M,K]
    const uint16_t* __restrict__ B,   // bf16 bits, [N,K]
    const float* __restrict__ bias,   // [N]
    float* __restrict__ C,            // [M,N]
    int M, int N, int K)
{
    __shared__ uint4 sh[8][1024];     // 128 KiB

    const int tid  = threadIdx.x;
    const int lane = tid & 63;
    const int wave = tid >> 6;
    const int wm = wave >> 2, wn = wave & 3;
    const int lm = lane & 15, g4 = lane >> 4;
    const int bn = blockIdx.x, bm = blockIdx.y;

    const int NT  = K >> 6;           // K-tiles (BK=64); K % 128 == 0 assumed
    const int NHT = NT << 2;          // half-tiles total

    // ---- staging precompute: LDS pos p -> source chunk c = p ^ ((p>>3)&7)
    const int p0 = tid, p1 = 512 + tid;
    const int c0 = p0 ^ ((p0 >> 3) & 7);
    const int c1 = p1 ^ ((p1 >> 3) & 7);
    const uint16_t* asrc0 = A + (size_t)(bm * BM + (c0 >> 2)) * K + (c0 & 3) * 8;
    const uint16_t* asrc1 = A + (size_t)(bm * BM + (c1 >> 2)) * K + (c1 & 3) * 8;
    const uint16_t* bsrc0 = B + (size_t)(bn * BN + (c0 >> 2)) * K + (c0 & 3) * 8;
    const uint16_t* bsrc1 = B + (size_t)(bn * BN + (c1 >> 2)) * K + (c1 & 3) * 8;
    char* ldsd0 = (char*)&sh[0][0] + p0 * 16;
    char* ldsd1 = (char*)&sh[0][0] + p1 * 16;

    // ---- swizzled ds_read chunk positions (per-thread constants)
    int aPos[8], bPos[4];
#pragma unroll
    for (int f = 0; f < 8; ++f) {
        int c = (wm * 128 + f * 16 + lm) * 4 + g4;
        aPos[f] = c ^ ((c >> 3) & 7);
    }
#pragma unroll
    for (int f = 0; f < 4; ++f) {
        int c = (wn * 64 + f * 16 + lm) * 4 + g4;
        bPos[f] = c ^ ((c >> 3) & 7);
    }

    f32x4 acc[8][4];
#pragma unroll
    for (int i = 0; i < 8; ++i)
#pragma unroll
        for (int j = 0; j < 4; ++j) acc[i][j] = (f32x4){0.f, 0.f, 0.f, 0.f};

    bf16x8 a0[4], a1[4], b0[4], b1[4];   // static frag double-buffers

#define STAGE(jj) do {                                                        \
    int _j = (jj);                                                            \
    int _koff = (_j < NHT) ? (((_j >> 2) << 6) | (((_j >> 1) & 1) << 5)) : 0; \
    int _sb = (_j & 7) << 14;                                                 \
    const uint16_t* _s0 = (_j & 1) ? bsrc0 : asrc0;                           \
    const uint16_t* _s1 = (_j & 1) ? bsrc1 : asrc1;                           \
    __builtin_amdgcn_global_load_lds(                                         \
        (const __attribute__((address_space(1))) unsigned int*)(_s0 + _koff), \
        (__attribute__((address_space(3))) unsigned int*)(ldsd0 + _sb),       \
        16, 0, 0);                                                            \
    __builtin_amdgcn_global_load_lds(                                         \
        (const __attribute__((address_space(1))) unsigned int*)(_s1 + _koff), \
        (__attribute__((address_space(3))) unsigned int*)(ldsd1 + _sb),       \
        16, 0, 0);                                                            \
} while (0)

// WIN(ARH, CA, CB, NA, NSA, NRH, LOADB, NB, NSB, SJ, GATE)
//   compute: acc rows 4*ARH.. with frags CA x CB (read LAST window)
//   then load: NA <- A slot NSA rows 4*NRH.. ; if LOADB: NB <- B slot NSB
#define WIN(ARH, CA, CB, NA, NSA, NRH, LOADB, NB, NSB, SJ, GATE) do {         \
    __builtin_amdgcn_s_setprio(1);                                            \
    _Pragma("unroll")                                                         \
    for (int _i = 0; _i < 4; ++_i)                                            \
        _Pragma("unroll")                                                     \
        for (int _jj = 0; _jj < 4; ++_jj)                                     \
            acc[4*(ARH) + _i][_jj] = __builtin_amdgcn_mfma_f32_16x16x32_bf16( \
                CA[_i], CB[_jj], acc[4*(ARH) + _i][_jj], 0, 0, 0);            \
    __builtin_amdgcn_s_setprio(0);                                            \
    _Pragma("unroll")                                                         \
    for (int _i = 0; _i < 4; ++_i)                                            \
        NA[_i] = __builtin_bit_cast(bf16x8, sh[NSA][aPos[4*(NRH) + _i]]);     \
    if (LOADB) {                                                              \
        _Pragma("unroll")                                                     \
        for (int _jj = 0; _jj < 4; ++_jj)                                     \
            NB[_jj] = __builtin_bit_cast(bf16x8, sh[NSB][bPos[_jj]]);         \
    }                                                                         \
    STAGE(hb + (SJ));                                                         \
    if (GATE) asm volatile("s_waitcnt vmcnt(6)" ::: "memory");                \
    __builtin_amdgcn_sched_barrier(0);                                        \
    __builtin_amdgcn_s_barrier();                                             \
} while (0)

    // prologue: stage h0..h5; h0,h1 landed; publish; preload window-1 frags
    STAGE(0); STAGE(1); STAGE(2); STAGE(3); STAGE(4); STAGE(5);
    asm volatile("s_waitcnt vmcnt(8)" ::: "memory");
    __builtin_amdgcn_s_barrier();
#pragma unroll
    for (int i = 0; i < 4; ++i)
        a1[i] = __builtin_bit_cast(bf16x8, sh[0][aPos[i]]);
#pragma unroll
    for (int j = 0; j < 4; ++j)
        b0[j] = __builtin_bit_cast(bf16x8, sh[1][bPos[j]]);

    const int NT2 = NT >> 1;
    for (int it2 = 0; it2 < NT2; ++it2) {
        const int hb = it2 << 3;
        WIN(0, a1, b0, a0, 0, 1, 0, b1, 0,  6, 1);   // q1 (0,0,rh0)
        WIN(1, a0, b0, a1, 2, 0, 1, b1, 3,  7, 0);   // q2 (0,0,rh1)
        WIN(0, a1, b1, a0, 2, 1, 0, b0, 0,  8, 1);   // q3 (0,1,rh0)
        WIN(1, a0, b1, a1, 4, 0, 1, b0, 5,  9, 0);   // q4 (0,1,rh1)
        WIN(0, a1, b0, a0, 4, 1, 0, b1, 0, 10, 1);   // q5 (1,0,rh0)
        WIN(1, a0, b0, a1, 6, 0, 1, b1, 7, 11, 0);   // q6 (1,0,rh1)
        WIN(0, a1, b1, a0, 6, 1, 0, b0, 0, 12, 1);   // q7 (1,1,rh0)
        WIN(1, a0, b1, a1, 0, 0, 1, b0, 1, 13, 0);   // q8 (1,1,rh1)
    }
    asm volatile("s_waitcnt vmcnt(0) lgkmcnt(0)" ::: "memory");

#undef WIN
#undef STAGE

    // Epilogue. C/D layout: col = lane&15, row = (lane>>4)*4 + reg  [m89/m91]
#pragma unroll
    for (int j = 0; j < 4; ++j) {
        int col = bn * BN + wn * 64 + j * 16 + lm;
        float bj = bias[col];
#pragma unroll
        for (int i = 0; i < 8; ++i) {
            int row0 = bm * BM + wm * 128 + i * 16 + g4 * 4;
#pragma unroll
            for (int r = 0; r < 4; ++r) {
                C[(size_t)(row0 + r) * (size_t)N + col] = acc[i][j][r] + bj;
            }
        }
    }
}

// ---------------- launch ----------------

extern "C" void kernel_launch(void* const* d_in, const int* in_sizes, int n_in,
                              void* d_out, int out_size, void* d_ws, size_t ws_size,
                              hipStream_t stream)
{
    const float* x        = (const float*)d_in[0];
    const float* w        = (const float*)d_in[1];
    const float* bias     = (const float*)d_in[2];
    const float* signs_in = (const float*)d_in[3];
    // d_in[4] = signs_grad: unused in forward

    const int OUT = in_sizes[2];              // 4096
    const int IN  = in_sizes[1] / OUT;        // 4096
    const int M   = in_sizes[0] / IN;         // 8192

    uint16_t* xq = (uint16_t*)d_ws;                    // [M, IN] bf16
    uint16_t* wq = xq + (size_t)M * (size_t)IN;        // [OUT, IN] bf16
    (void)ws_size; (void)n_in; (void)out_size;

    int ngx = (int)((size_t)M * IN / 16);
    int ngw = (int)((size_t)OUT * IN / 16);
    quant_rht_kernel<<<(ngx + 255) / 256, 256, 0, stream>>>(x, signs_in, xq, ngx);
    quant_rht_kernel<<<(ngw + 255) / 256, 256, 0, stream>>>(w, signs_in, wq, ngw);

    dim3 grid(OUT / BN, M / BM);
    gemm_bt_bias<<<grid, 512, 0, stream>>>(xq, wq, bias, (float*)d_out, M, OUT, IN);
}